// Round 2
// baseline (10299.352 us; speedup 1.0000x reference)
//
#include <hip/hip_runtime.h>

#define NATOMS 100000
#define NPAIRS 3200000
// F_ATOM=75, F_PAIR=14, H=50, F_OUT=50

__device__ __forceinline__ unsigned short f2bf(float f) {
    unsigned int u = __float_as_uint(f);
    unsigned int r = (u + 0x7fffu + ((u >> 16) & 1u)) >> 16;   // RNE
    return (unsigned short)r;
}
__device__ __forceinline__ float bflo(unsigned int u) { return __uint_as_float(u << 16); }
__device__ __forceinline__ float bfhi(unsigned int u) { return __uint_as_float(u & 0xffff0000u); }
__device__ __forceinline__ unsigned int pack2(float a, float b) {
    return (unsigned int)f2bf(a) | ((unsigned int)f2bf(b) << 16);
}

// XA row layout (uints, stride 56 per atom = 224 B, 16B aligned):
//   uints 0..24  : X1' = af@W_AP[:, :75].T + b_AP   (elems 0..49, pair-packed)
//   uints 25..27 : pad
//   uints 28..52 : X2  = af@W_AP[:, 75:].T          (elems 0..49)
//   uints 53..55 : pad

// K1: per-atom precompute: AA (f32) and XA (bf16 packed)
__global__ __launch_bounds__(256) void k_atom_pre(
    const float* __restrict__ af,
    const float* __restrict__ W_AA, const float* __restrict__ b_AA,
    const float* __restrict__ W_AP, const float* __restrict__ b_AP,
    float* __restrict__ AA, unsigned int* __restrict__ XAu)
{
    int a = blockIdx.x * 256 + threadIdx.x;
    if (a >= NATOMS) return;
    const float* ar = af + (size_t)a * 75;
    float x[75];
#pragma unroll
    for (int k = 0; k < 75; ++k) x[k] = ar[k];

    // AA = relu(af@W_AA.T + b_AA), f32, two chunks of 25
    float* aout = AA + (size_t)a * 50;
#pragma unroll
    for (int jc = 0; jc < 50; jc += 25) {
        float acc[25];
#pragma unroll
        for (int j = 0; j < 25; ++j) acc[j] = b_AA[jc + j];
#pragma unroll
        for (int k = 0; k < 75; ++k) {
#pragma unroll
            for (int j = 0; j < 25; ++j)
                acc[j] = fmaf(x[k], W_AA[(jc + j) * 75 + k], acc[j]);
        }
#pragma unroll
        for (int j = 0; j < 25; ++j) aout[jc + j] = fmaxf(acc[j], 0.0f);
    }

    unsigned int* xout = XAu + (size_t)a * 56;

    // X1' chunk A: elems 0..25 (n=26) -> uints 0..12
    {
        float acc[26];
#pragma unroll
        for (int j = 0; j < 26; ++j) acc[j] = b_AP[j];
#pragma unroll
        for (int k = 0; k < 75; ++k)
#pragma unroll
            for (int j = 0; j < 26; ++j)
                acc[j] = fmaf(x[k], W_AP[j * 150 + k], acc[j]);
#pragma unroll
        for (int u = 0; u < 13; ++u) xout[u] = pack2(acc[2 * u], acc[2 * u + 1]);
    }
    // X1' chunk B: elems 26..49 (n=24) -> uints 13..24
    {
        float acc[24];
#pragma unroll
        for (int j = 0; j < 24; ++j) acc[j] = b_AP[26 + j];
#pragma unroll
        for (int k = 0; k < 75; ++k)
#pragma unroll
            for (int j = 0; j < 24; ++j)
                acc[j] = fmaf(x[k], W_AP[(26 + j) * 150 + k], acc[j]);
#pragma unroll
        for (int u = 0; u < 12; ++u) xout[13 + u] = pack2(acc[2 * u], acc[2 * u + 1]);
    }
    // X2 chunk A: elems 0..25 -> uints 28..40
    {
        float acc[26];
#pragma unroll
        for (int j = 0; j < 26; ++j) acc[j] = 0.0f;
#pragma unroll
        for (int k = 0; k < 75; ++k)
#pragma unroll
            for (int j = 0; j < 26; ++j)
                acc[j] = fmaf(x[k], W_AP[j * 150 + 75 + k], acc[j]);
#pragma unroll
        for (int u = 0; u < 13; ++u) xout[28 + u] = pack2(acc[2 * u], acc[2 * u + 1]);
    }
    // X2 chunk B: elems 26..49 -> uints 41..52
    {
        float acc[24];
#pragma unroll
        for (int j = 0; j < 24; ++j) acc[j] = 0.0f;
#pragma unroll
        for (int k = 0; k < 75; ++k)
#pragma unroll
            for (int j = 0; j < 24; ++j)
                acc[j] = fmaf(x[k], W_AP[(26 + j) * 150 + 75 + k], acc[j]);
#pragma unroll
        for (int u = 0; u < 12; ++u) xout[41 + u] = pack2(acc[2 * u], acc[2 * u + 1]);
    }
}

// K2: per-pair fused kernel, one thread per pair, 256 pairs/block.
__global__ __launch_bounds__(256, 4) void k_pair(
    const float* __restrict__ pf,
    const int* __restrict__ psplit,
    const int* __restrict__ a2p,
    const float* __restrict__ W_PA, const float* __restrict__ b_PA,
    const float* __restrict__ W_PP, const float* __restrict__ b_PP,
    const float* __restrict__ W_P,  const float* __restrict__ b_P,
    const unsigned int* __restrict__ XAu,
    float* __restrict__ PAsum,
    float* __restrict__ Pout)
{
    __shared__ unsigned int pa_lds[256 * 27];  // 25 used/row, stride 27 (odd -> 2-way max)
    __shared__ int head_list[256];
    __shared__ int ps_lds[256];
    __shared__ int nheads;

    const int t = threadIdx.x;
    const int p = blockIdx.x * 256 + t;       // NPAIRS == 12500*256
    if (t == 0) nheads = 0;

    // pair features (14 f32, 8B-aligned rows)
    float x[14];
    {
        const float2* pr2 = (const float2*)(pf + (size_t)p * 14);
#pragma unroll
        for (int k = 0; k < 7; ++k) {
            float2 v = pr2[k];
            x[2 * k] = v.x; x[2 * k + 1] = v.y;
        }
    }
    ps_lds[t] = psplit[p];

    // PA = relu(pf@W_PA.T + b_PA) -> packed bf16 LDS
    {
        float pa[50];
#pragma unroll
        for (int j = 0; j < 50; ++j) pa[j] = b_PA[j];
#pragma unroll
        for (int k = 0; k < 14; ++k)
#pragma unroll
            for (int j = 0; j < 50; ++j)
                pa[j] = fmaf(x[k], W_PA[j * 14 + k], pa[j]);
#pragma unroll
        for (int u = 0; u < 25; ++u)
            pa_lds[t * 27 + u] = pack2(fmaxf(pa[2 * u], 0.0f), fmaxf(pa[2 * u + 1], 0.0f));
    }

    // S via bf16 gather: s[f] = relu(X1'_i[f]+X2_j[f]) + relu(X1'_j[f]+X2_i[f])
    float s[50];
    {
        const int2 ij = ((const int2*)a2p)[p];
        const uint4* xi4 = (const uint4*)(XAu + (size_t)ij.x * 56);
        const uint4* xj4 = (const uint4*)(XAu + (size_t)ij.y * 56);
#pragma unroll
        for (int c = 0; c < 6; ++c) {
            uint4 A = xi4[c];       // X1'_i elems 8c..8c+7
            uint4 B = xj4[7 + c];   // X2_j
            uint4 C = xj4[c];       // X1'_j
            uint4 D = xi4[7 + c];   // X2_i
            s[8 * c + 0] = fmaxf(bflo(A.x) + bflo(B.x), 0.f) + fmaxf(bflo(C.x) + bflo(D.x), 0.f);
            s[8 * c + 1] = fmaxf(bfhi(A.x) + bfhi(B.x), 0.f) + fmaxf(bfhi(C.x) + bfhi(D.x), 0.f);
            s[8 * c + 2] = fmaxf(bflo(A.y) + bflo(B.y), 0.f) + fmaxf(bflo(C.y) + bflo(D.y), 0.f);
            s[8 * c + 3] = fmaxf(bfhi(A.y) + bfhi(B.y), 0.f) + fmaxf(bfhi(C.y) + bfhi(D.y), 0.f);
            s[8 * c + 4] = fmaxf(bflo(A.z) + bflo(B.z), 0.f) + fmaxf(bflo(C.z) + bflo(D.z), 0.f);
            s[8 * c + 5] = fmaxf(bfhi(A.z) + bfhi(B.z), 0.f) + fmaxf(bfhi(C.z) + bfhi(D.z), 0.f);
            s[8 * c + 6] = fmaxf(bflo(A.w) + bflo(B.w), 0.f) + fmaxf(bflo(C.w) + bflo(D.w), 0.f);
            s[8 * c + 7] = fmaxf(bfhi(A.w) + bfhi(B.w), 0.f) + fmaxf(bfhi(C.w) + bfhi(D.w), 0.f);
        }
        // tail f=48,49
        const unsigned int* xiu = XAu + (size_t)ij.x * 56;
        const unsigned int* xju = XAu + (size_t)ij.y * 56;
        unsigned int A = xiu[24], B = xju[52], C = xju[24], D = xiu[52];
        s[48] = fmaxf(bflo(A) + bflo(B), 0.f) + fmaxf(bflo(C) + bflo(D), 0.f);
        s[49] = fmaxf(bfhi(A) + bfhi(B), 0.f) + fmaxf(bfhi(C) + bfhi(D), 0.f);
    }

    // PP = relu(pf@W_PP.T + b_PP)
    float pp[50];
#pragma unroll
    for (int j = 0; j < 50; ++j) pp[j] = b_PP[j];
#pragma unroll
    for (int k = 0; k < 14; ++k)
#pragma unroll
        for (int j = 0; j < 50; ++j)
            pp[j] = fmaf(x[k], W_PP[j * 14 + k], pp[j]);
#pragma unroll
    for (int j = 0; j < 50; ++j) pp[j] = fmaxf(pp[j], 0.0f);

    // P = relu(s @ W_P[:,:50].T + pp @ W_P[:,50:].T + b_P), o-chunks of 25
    float* po = Pout + (size_t)p * 50;
#pragma unroll
    for (int oc = 0; oc < 50; oc += 25) {
        float acc[25];
#pragma unroll
        for (int o = 0; o < 25; ++o) acc[o] = b_P[oc + o];
#pragma unroll
        for (int f = 0; f < 50; ++f)
#pragma unroll
            for (int o = 0; o < 25; ++o)
                acc[o] = fmaf(s[f], W_P[(oc + o) * 100 + f], acc[o]);
#pragma unroll
        for (int f = 0; f < 50; ++f)
#pragma unroll
            for (int o = 0; o < 25; ++o)
                acc[o] = fmaf(pp[f], W_P[(oc + o) * 100 + 50 + f], acc[o]);
#pragma unroll
        for (int o = 0; o < 25; ++o) po[oc + o] = fmaxf(acc[o], 0.0f);
    }

    // segment-sum of PA (pair_split sorted): per-block run reduction + atomics
    __syncthreads();
    bool head = (t == 0) || (ps_lds[t] != ps_lds[t - 1]);
    if (head) {
        int idx = atomicAdd(&nheads, 1);
        head_list[idx] = t;
    }
    __syncthreads();

    const int nh = nheads;
    for (int w = t; w < nh * 25; w += 256) {
        const int r0  = head_list[w / 25];
        const int jc  = w % 25;
        const int seg = ps_lds[r0];
        float a0 = 0.0f, a1 = 0.0f;
        int rr = r0;
        do {
            unsigned int u = pa_lds[rr * 27 + jc];
            a0 += bflo(u);
            a1 += bfhi(u);
            ++rr;
        } while (rr < 256 && ps_lds[rr] == seg);
        atomicAdd(&PAsum[(size_t)seg * 50 + 2 * jc],     a0);
        atomicAdd(&PAsum[(size_t)seg * 50 + 2 * jc + 1], a1);
    }
}

// K3: A = relu(concat(AA, PAsum) @ W_A.T + b_A)
__global__ __launch_bounds__(256) void k_atom_final(
    const float* __restrict__ AA, const float* __restrict__ PAsum,
    const float* __restrict__ W_A, const float* __restrict__ b_A,
    float* __restrict__ Aout)
{
    int a = blockIdx.x * 256 + threadIdx.x;
    if (a >= NATOMS) return;
    float v[100];
    const float* p1 = AA + (size_t)a * 50;
    const float* p2 = PAsum + (size_t)a * 50;
#pragma unroll
    for (int f = 0; f < 50; ++f) v[f] = p1[f];
#pragma unroll
    for (int f = 0; f < 50; ++f) v[50 + f] = p2[f];
    float* ao = Aout + (size_t)a * 50;
#pragma unroll
    for (int oc = 0; oc < 50; oc += 25) {
        float acc[25];
#pragma unroll
        for (int o = 0; o < 25; ++o) acc[o] = b_A[oc + o];
#pragma unroll
        for (int f = 0; f < 100; ++f)
#pragma unroll
            for (int o = 0; o < 25; ++o)
                acc[o] = fmaf(v[f], W_A[(oc + o) * 100 + f], acc[o]);
#pragma unroll
        for (int o = 0; o < 25; ++o) ao[oc + o] = fmaxf(acc[o], 0.0f);
    }
}

extern "C" void kernel_launch(void* const* d_in, const int* in_sizes, int n_in,
                              void* d_out, int out_size, void* d_ws, size_t ws_size,
                              hipStream_t stream)
{
    const float* atom_features = (const float*)d_in[0];
    const float* pair_features = (const float*)d_in[1];
    const int*   pair_split    = (const int*)d_in[2];
    const int*   atom_to_pair  = (const int*)d_in[3];
    const float* W_AA = (const float*)d_in[4];
    const float* b_AA = (const float*)d_in[5];
    const float* W_PA = (const float*)d_in[6];
    const float* b_PA = (const float*)d_in[7];
    const float* W_A  = (const float*)d_in[8];
    const float* b_A  = (const float*)d_in[9];
    const float* W_AP = (const float*)d_in[10];
    const float* b_AP = (const float*)d_in[11];
    const float* W_PP = (const float*)d_in[12];
    const float* b_PP = (const float*)d_in[13];
    const float* W_P  = (const float*)d_in[14];
    const float* b_P  = (const float*)d_in[15];

    float* out   = (float*)d_out;
    float* A_out = out;                              // [NATOMS,50]
    float* P_out = out + (size_t)NATOMS * 50;        // [NPAIRS,50]

    float*        AA    = (float*)d_ws;                        // 5,000,000 f32
    unsigned int* XAu   = (unsigned int*)(AA + (size_t)NATOMS * 50);  // 5,600,000 u32
    float*        PAsum = (float*)(XAu + (size_t)NATOMS * 56);        // 5,000,000 f32

    hipMemsetAsync(PAsum, 0, (size_t)NATOMS * 50 * sizeof(float), stream);

    k_atom_pre<<<(NATOMS + 255) / 256, 256, 0, stream>>>(
        atom_features, W_AA, b_AA, W_AP, b_AP, AA, XAu);

    k_pair<<<NPAIRS / 256, 256, 0, stream>>>(
        pair_features, pair_split, atom_to_pair,
        W_PA, b_PA, W_PP, b_PP, W_P, b_P,
        XAu, PAsum, P_out);

    k_atom_final<<<(NATOMS + 255) / 256, 256, 0, stream>>>(
        AA, PAsum, W_A, b_A, A_out);
}

// Round 3
// 9740.801 us; speedup vs baseline: 1.0573x; 1.0573x over previous
//
#include <hip/hip_runtime.h>

#define NATOMS 100000
#define NPAIRS 3200000
// F_ATOM=75, F_PAIR=14, H=50, F_OUT=50

__device__ __forceinline__ unsigned short f2bf(float f) {
    unsigned int u = __float_as_uint(f);
    unsigned int r = (u + 0x7fffu + ((u >> 16) & 1u)) >> 16;   // RNE
    return (unsigned short)r;
}
__device__ __forceinline__ float bflo(unsigned int u) { return __uint_as_float(u << 16); }
__device__ __forceinline__ float bfhi(unsigned int u) { return __uint_as_float(u & 0xffff0000u); }
__device__ __forceinline__ unsigned int pack2(float a, float b) {
    return (unsigned int)f2bf(a) | ((unsigned int)f2bf(b) << 16);
}

// XA row layout (uints, stride 56 per atom = 224 B, 16B aligned):
//   uints 0..24  : X1' = af@W_AP[:, :75].T + b_AP   (elems 0..49, pair-packed)
//   uints 25..27 : pad
//   uints 28..52 : X2  = af@W_AP[:, 75:].T          (elems 0..49)
//   uints 53..55 : pad

// K1: per-atom precompute: AA (f32) and XA (bf16 packed)
__global__ __launch_bounds__(256) void k_atom_pre(
    const float* __restrict__ af,
    const float* __restrict__ W_AA, const float* __restrict__ b_AA,
    const float* __restrict__ W_AP, const float* __restrict__ b_AP,
    float* __restrict__ AA, unsigned int* __restrict__ XAu)
{
    int a = blockIdx.x * 256 + threadIdx.x;
    if (a >= NATOMS) return;
    const float* ar = af + (size_t)a * 75;
    float x[75];
#pragma unroll
    for (int k = 0; k < 75; ++k) x[k] = ar[k];

    // AA = relu(af@W_AA.T + b_AA), f32, two chunks of 25
    float* aout = AA + (size_t)a * 50;
#pragma unroll
    for (int jc = 0; jc < 50; jc += 25) {
        float acc[25];
#pragma unroll
        for (int j = 0; j < 25; ++j) acc[j] = b_AA[jc + j];
#pragma unroll
        for (int k = 0; k < 75; ++k) {
#pragma unroll
            for (int j = 0; j < 25; ++j)
                acc[j] = fmaf(x[k], W_AA[(jc + j) * 75 + k], acc[j]);
        }
#pragma unroll
        for (int j = 0; j < 25; ++j) aout[jc + j] = fmaxf(acc[j], 0.0f);
    }

    unsigned int* xout = XAu + (size_t)a * 56;

    // X1' chunk A: elems 0..25 (n=26) -> uints 0..12
    {
        float acc[26];
#pragma unroll
        for (int j = 0; j < 26; ++j) acc[j] = b_AP[j];
#pragma unroll
        for (int k = 0; k < 75; ++k)
#pragma unroll
            for (int j = 0; j < 26; ++j)
                acc[j] = fmaf(x[k], W_AP[j * 150 + k], acc[j]);
#pragma unroll
        for (int u = 0; u < 13; ++u) xout[u] = pack2(acc[2 * u], acc[2 * u + 1]);
    }
    // X1' chunk B: elems 26..49 (n=24) -> uints 13..24
    {
        float acc[24];
#pragma unroll
        for (int j = 0; j < 24; ++j) acc[j] = b_AP[26 + j];
#pragma unroll
        for (int k = 0; k < 75; ++k)
#pragma unroll
            for (int j = 0; j < 24; ++j)
                acc[j] = fmaf(x[k], W_AP[(26 + j) * 150 + k], acc[j]);
#pragma unroll
        for (int u = 0; u < 12; ++u) xout[13 + u] = pack2(acc[2 * u], acc[2 * u + 1]);
    }
    // X2 chunk A: elems 0..25 -> uints 28..40
    {
        float acc[26];
#pragma unroll
        for (int j = 0; j < 26; ++j) acc[j] = 0.0f;
#pragma unroll
        for (int k = 0; k < 75; ++k)
#pragma unroll
            for (int j = 0; j < 26; ++j)
                acc[j] = fmaf(x[k], W_AP[j * 150 + 75 + k], acc[j]);
#pragma unroll
        for (int u = 0; u < 13; ++u) xout[28 + u] = pack2(acc[2 * u], acc[2 * u + 1]);
    }
    // X2 chunk B: elems 26..49 -> uints 41..52
    {
        float acc[24];
#pragma unroll
        for (int j = 0; j < 24; ++j) acc[j] = 0.0f;
#pragma unroll
        for (int k = 0; k < 75; ++k)
#pragma unroll
            for (int j = 0; j < 24; ++j)
                acc[j] = fmaf(x[k], W_AP[(26 + j) * 150 + 75 + k], acc[j]);
#pragma unroll
        for (int u = 0; u < 12; ++u) xout[41 + u] = pack2(acc[2 * u], acc[2 * u + 1]);
    }
}

// K2: per-pair fused kernel, one thread per pair, 256 pairs/block.
// NOTE: plain __launch_bounds__(256) — round 2 proved (256,4) forces 64 VGPR -> spills.
__global__ __launch_bounds__(256) void k_pair(
    const float* __restrict__ pf,
    const int* __restrict__ psplit,
    const int* __restrict__ a2p,
    const float* __restrict__ W_PA, const float* __restrict__ b_PA,
    const float* __restrict__ W_PP, const float* __restrict__ b_PP,
    const float* __restrict__ W_P,  const float* __restrict__ b_P,
    const unsigned int* __restrict__ XAu,
    float* __restrict__ PAsum,
    float* __restrict__ Pout)
{
    __shared__ unsigned int pa_lds[256 * 27];  // 25 used/row, stride 27 (odd -> 2-way max)
    __shared__ int head_list[256];
    __shared__ int ps_lds[256];
    __shared__ int nheads;

    const int t = threadIdx.x;
    const int p = blockIdx.x * 256 + t;       // NPAIRS == 12500*256
    if (t == 0) nheads = 0;

    // pair features (14 f32, 8B-aligned rows)
    float x[14];
    {
        const float2* pr2 = (const float2*)(pf + (size_t)p * 14);
#pragma unroll
        for (int k = 0; k < 7; ++k) {
            float2 v = pr2[k];
            x[2 * k] = v.x; x[2 * k + 1] = v.y;
        }
    }
    ps_lds[t] = psplit[p];

    // PA = relu(pf@W_PA.T + b_PA) -> packed bf16 LDS
    {
        float pa[50];
#pragma unroll
        for (int j = 0; j < 50; ++j) pa[j] = b_PA[j];
#pragma unroll
        for (int k = 0; k < 14; ++k)
#pragma unroll
            for (int j = 0; j < 50; ++j)
                pa[j] = fmaf(x[k], W_PA[j * 14 + k], pa[j]);
#pragma unroll
        for (int u = 0; u < 25; ++u)
            pa_lds[t * 27 + u] = pack2(fmaxf(pa[2 * u], 0.0f), fmaxf(pa[2 * u + 1], 0.0f));
    }

    // S via bf16 gather: s[f] = relu(X1'_i[f]+X2_j[f]) + relu(X1'_j[f]+X2_i[f])
    float s[50];
    {
        const int2 ij = ((const int2*)a2p)[p];
        const uint4* xi4 = (const uint4*)(XAu + (size_t)ij.x * 56);
        const uint4* xj4 = (const uint4*)(XAu + (size_t)ij.y * 56);
#pragma unroll
        for (int c = 0; c < 6; ++c) {
            uint4 A = xi4[c];       // X1'_i elems 8c..8c+7
            uint4 B = xj4[7 + c];   // X2_j
            uint4 C = xj4[c];       // X1'_j
            uint4 D = xi4[7 + c];   // X2_i
            s[8 * c + 0] = fmaxf(bflo(A.x) + bflo(B.x), 0.f) + fmaxf(bflo(C.x) + bflo(D.x), 0.f);
            s[8 * c + 1] = fmaxf(bfhi(A.x) + bfhi(B.x), 0.f) + fmaxf(bfhi(C.x) + bfhi(D.x), 0.f);
            s[8 * c + 2] = fmaxf(bflo(A.y) + bflo(B.y), 0.f) + fmaxf(bflo(C.y) + bflo(D.y), 0.f);
            s[8 * c + 3] = fmaxf(bfhi(A.y) + bfhi(B.y), 0.f) + fmaxf(bfhi(C.y) + bfhi(D.y), 0.f);
            s[8 * c + 4] = fmaxf(bflo(A.z) + bflo(B.z), 0.f) + fmaxf(bflo(C.z) + bflo(D.z), 0.f);
            s[8 * c + 5] = fmaxf(bfhi(A.z) + bfhi(B.z), 0.f) + fmaxf(bfhi(C.z) + bfhi(D.z), 0.f);
            s[8 * c + 6] = fmaxf(bflo(A.w) + bflo(B.w), 0.f) + fmaxf(bflo(C.w) + bflo(D.w), 0.f);
            s[8 * c + 7] = fmaxf(bfhi(A.w) + bfhi(B.w), 0.f) + fmaxf(bfhi(C.w) + bfhi(D.w), 0.f);
        }
        // tail f=48,49
        const unsigned int* xiu = XAu + (size_t)ij.x * 56;
        const unsigned int* xju = XAu + (size_t)ij.y * 56;
        unsigned int A = xiu[24], B = xju[52], C = xju[24], D = xiu[52];
        s[48] = fmaxf(bflo(A) + bflo(B), 0.f) + fmaxf(bflo(C) + bflo(D), 0.f);
        s[49] = fmaxf(bfhi(A) + bfhi(B), 0.f) + fmaxf(bfhi(C) + bfhi(D), 0.f);
    }

    // PP = relu(pf@W_PP.T + b_PP)
    float pp[50];
#pragma unroll
    for (int j = 0; j < 50; ++j) pp[j] = b_PP[j];
#pragma unroll
    for (int k = 0; k < 14; ++k)
#pragma unroll
        for (int j = 0; j < 50; ++j)
            pp[j] = fmaf(x[k], W_PP[j * 14 + k], pp[j]);
#pragma unroll
    for (int j = 0; j < 50; ++j) pp[j] = fmaxf(pp[j], 0.0f);

    // P = relu(s @ W_P[:,:50].T + pp @ W_P[:,50:].T + b_P), o-chunks of 25
    float* po = Pout + (size_t)p * 50;
#pragma unroll
    for (int oc = 0; oc < 50; oc += 25) {
        float acc[25];
#pragma unroll
        for (int o = 0; o < 25; ++o) acc[o] = b_P[oc + o];
#pragma unroll
        for (int f = 0; f < 50; ++f)
#pragma unroll
            for (int o = 0; o < 25; ++o)
                acc[o] = fmaf(s[f], W_P[(oc + o) * 100 + f], acc[o]);
#pragma unroll
        for (int f = 0; f < 50; ++f)
#pragma unroll
            for (int o = 0; o < 25; ++o)
                acc[o] = fmaf(pp[f], W_P[(oc + o) * 100 + 50 + f], acc[o]);
#pragma unroll
        for (int o = 0; o < 25; ++o) po[oc + o] = fmaxf(acc[o], 0.0f);
    }

    // segment-sum of PA (pair_split sorted): per-block run reduction + atomics
    __syncthreads();
    bool head = (t == 0) || (ps_lds[t] != ps_lds[t - 1]);
    if (head) {
        int idx = atomicAdd(&nheads, 1);
        head_list[idx] = t;
    }
    __syncthreads();

    const int nh = nheads;
    for (int w = t; w < nh * 25; w += 256) {
        const int r0  = head_list[w / 25];
        const int jc  = w % 25;
        const int seg = ps_lds[r0];
        float a0 = 0.0f, a1 = 0.0f;
        int rr = r0;
        do {
            unsigned int u = pa_lds[rr * 27 + jc];
            a0 += bflo(u);
            a1 += bfhi(u);
            ++rr;
        } while (rr < 256 && ps_lds[rr] == seg);
        atomicAdd(&PAsum[(size_t)seg * 50 + 2 * jc],     a0);
        atomicAdd(&PAsum[(size_t)seg * 50 + 2 * jc + 1], a1);
    }
}

// K3: A = relu(concat(AA, PAsum) @ W_A.T + b_A)
__global__ __launch_bounds__(256) void k_atom_final(
    const float* __restrict__ AA, const float* __restrict__ PAsum,
    const float* __restrict__ W_A, const float* __restrict__ b_A,
    float* __restrict__ Aout)
{
    int a = blockIdx.x * 256 + threadIdx.x;
    if (a >= NATOMS) return;
    float v[100];
    const float* p1 = AA + (size_t)a * 50;
    const float* p2 = PAsum + (size_t)a * 50;
#pragma unroll
    for (int f = 0; f < 50; ++f) v[f] = p1[f];
#pragma unroll
    for (int f = 0; f < 50; ++f) v[50 + f] = p2[f];
    float* ao = Aout + (size_t)a * 50;
#pragma unroll
    for (int oc = 0; oc < 50; oc += 25) {
        float acc[25];
#pragma unroll
        for (int o = 0; o < 25; ++o) acc[o] = b_A[oc + o];
#pragma unroll
        for (int f = 0; f < 100; ++f)
#pragma unroll
            for (int o = 0; o < 25; ++o)
                acc[o] = fmaf(v[f], W_A[(oc + o) * 100 + f], acc[o]);
#pragma unroll
        for (int o = 0; o < 25; ++o) ao[oc + o] = fmaxf(acc[o], 0.0f);
    }
}

extern "C" void kernel_launch(void* const* d_in, const int* in_sizes, int n_in,
                              void* d_out, int out_size, void* d_ws, size_t ws_size,
                              hipStream_t stream)
{
    const float* atom_features = (const float*)d_in[0];
    const float* pair_features = (const float*)d_in[1];
    const int*   pair_split    = (const int*)d_in[2];
    const int*   atom_to_pair  = (const int*)d_in[3];
    const float* W_AA = (const float*)d_in[4];
    const float* b_AA = (const float*)d_in[5];
    const float* W_PA = (const float*)d_in[6];
    const float* b_PA = (const float*)d_in[7];
    const float* W_A  = (const float*)d_in[8];
    const float* b_A  = (const float*)d_in[9];
    const float* W_AP = (const float*)d_in[10];
    const float* b_AP = (const float*)d_in[11];
    const float* W_PP = (const float*)d_in[12];
    const float* b_PP = (const float*)d_in[13];
    const float* W_P  = (const float*)d_in[14];
    const float* b_P  = (const float*)d_in[15];

    float* out   = (float*)d_out;
    float* A_out = out;                              // [NATOMS,50]
    float* P_out = out + (size_t)NATOMS * 50;        // [NPAIRS,50]

    float*        AA    = (float*)d_ws;                        // 5,000,000 f32
    unsigned int* XAu   = (unsigned int*)(AA + (size_t)NATOMS * 50);  // 5,600,000 u32
    float*        PAsum = (float*)(XAu + (size_t)NATOMS * 56);        // 5,000,000 f32

    hipMemsetAsync(PAsum, 0, (size_t)NATOMS * 50 * sizeof(float), stream);

    k_atom_pre<<<(NATOMS + 255) / 256, 256, 0, stream>>>(
        atom_features, W_AA, b_AA, W_AP, b_AP, AA, XAu);

    k_pair<<<NPAIRS / 256, 256, 0, stream>>>(
        pair_features, pair_split, atom_to_pair,
        W_PA, b_PA, W_PP, b_PP, W_P, b_P,
        XAu, PAsum, P_out);

    k_atom_final<<<(NATOMS + 255) / 256, 256, 0, stream>>>(
        AA, PAsum, W_A, b_A, A_out);
}

// Round 4
// 2381.494 us; speedup vs baseline: 4.3247x; 4.0902x over previous
//
#include <hip/hip_runtime.h>

#define NATOMS 100000
#define NPAIRS 3200000
// F_ATOM=75, F_PAIR=14, H=50, F_OUT=50

__device__ __forceinline__ unsigned short f2bf(float f) {
    unsigned int u = __float_as_uint(f);
    unsigned int r = (u + 0x7fffu + ((u >> 16) & 1u)) >> 16;   // RNE
    return (unsigned short)r;
}
__device__ __forceinline__ float bflo(unsigned int u) { return __uint_as_float(u << 16); }
__device__ __forceinline__ float bfhi(unsigned int u) { return __uint_as_float(u & 0xffff0000u); }
__device__ __forceinline__ unsigned int pack2(float a, float b) {
    return (unsigned int)f2bf(a) | ((unsigned int)f2bf(b) << 16);
}

// XA row layout (uints, stride 56 per atom = 224 B, 16B aligned):
//   uints 0..24  : X1' = af@W_AP[:, :75].T + b_AP   (pair-packed bf16)
//   uints 28..52 : X2  = af@W_AP[:, 75:].T
// (uints 25..27, 53..55 pad)

// K1: per-atom precompute. blockIdx.y = half (0: j=0..25, 1: j=26..49) so the
// weight-row address is wave-uniform. One thread per (atom, half).
__global__ __launch_bounds__(256, 2) void k_atom_pre(
    const float* __restrict__ af,
    const float* __restrict__ W_AA, const float* __restrict__ b_AA,
    const float* __restrict__ W_AP, const float* __restrict__ b_AP,
    float* __restrict__ AA, unsigned int* __restrict__ XAu)
{
    const int a = blockIdx.x * 256 + threadIdx.x;
    if (a >= NATOMS) return;
    const int half = blockIdx.y;

    const float* ar = af + (size_t)a * 75;
    float x[75];
#pragma unroll
    for (int k = 0; k < 75; ++k) x[k] = ar[k];

    const int jbase = half ? 26 : 0;
    const int jend  = half ? 50 : 26;

    // AA = relu(af@W_AA.T + b_AA), rows jbase..jend-1
    float* aout = AA + (size_t)a * 50;
#pragma unroll 2
    for (int j = jbase; j < jend; ++j) {
        const float* wr = W_AA + (size_t)j * 75;
        float acc = b_AA[j];
#pragma unroll
        for (int k = 0; k < 75; ++k) acc = fmaf(x[k], wr[k], acc);
        aout[j] = fmaxf(acc, 0.0f);
    }

    // X1' and X2 (bf16-packed), pair-of-rows per iteration
    unsigned int* xout = XAu + (size_t)a * 56;
    const int nu    = half ? 12 : 13;
    const int ubase = half ? 13 : 0;
#pragma unroll 1
    for (int u = 0; u < nu; ++u) {
        const int j = jbase + 2 * u;
        const float2* w0 = (const float2*)(W_AP + (size_t)j * 150);        // row j   (150 f32, 600B stride, 8B aligned)
        const float2* w1 = (const float2*)(W_AP + (size_t)(j + 1) * 150);  // row j+1
        float a0 = b_AP[j], a1 = b_AP[j + 1];   // X1' (first 75 cols)
        float c0 = 0.0f,   c1 = 0.0f;           // X2  (last 75 cols)
        // cols 0..74 in float2 chunks (37 float2 = 74) + scalar tail
#pragma unroll
        for (int q = 0; q < 37; ++q) {
            float2 wa = w0[q], wb = w1[q];
            a0 = fmaf(x[2 * q], wa.x, a0); a0 = fmaf(x[2 * q + 1], wa.y, a0);
            a1 = fmaf(x[2 * q], wb.x, a1); a1 = fmaf(x[2 * q + 1], wb.y, a1);
        }
        a0 = fmaf(x[74], ((const float*)w0)[74], a0);
        a1 = fmaf(x[74], ((const float*)w1)[74], a1);
        // cols 75..149: float2 starting at 75 is misaligned; read scalar pairs via float2 from 76
        c0 = fmaf(x[0], ((const float*)w0)[75], c0);
        c1 = fmaf(x[0], ((const float*)w1)[75], c1);
#pragma unroll
        for (int q = 0; q < 37; ++q) {
            float2 wa = ((const float2*)(((const float*)w0) + 76))[q];
            float2 wb = ((const float2*)(((const float*)w1) + 76))[q];
            c0 = fmaf(x[2 * q + 1], wa.x, c0); c0 = fmaf(x[2 * q + 2], wa.y, c0);
            c1 = fmaf(x[2 * q + 1], wb.x, c1); c1 = fmaf(x[2 * q + 2], wb.y, c1);
        }
        xout[ubase + u]      = pack2(a0, a1);
        xout[28 + ubase + u] = pack2(c0, c1);
    }
}

// K2: per-pair fused kernel, one thread per pair, 256 pairs/block.
// (256,2): explicit min-waves overrides the backend occupancy heuristic that
// allocated 80 VGPRs (< ~115 live) in round 3 and sent arrays to scratch.
__global__ __launch_bounds__(256, 2) void k_pair(
    const float* __restrict__ pf,
    const int* __restrict__ psplit,
    const int* __restrict__ a2p,
    const float* __restrict__ W_PA, const float* __restrict__ b_PA,
    const float* __restrict__ W_PP, const float* __restrict__ b_PP,
    const float* __restrict__ W_P,  const float* __restrict__ b_P,
    const unsigned int* __restrict__ XAu,
    float* __restrict__ PAsum,
    float* __restrict__ Pout)
{
    __shared__ unsigned int pa_lds[256 * 27];  // stride 27 (odd) per thread
    __shared__ int head_list[256];
    __shared__ int ps_lds[256];
    __shared__ int nheads;

    const int t = threadIdx.x;
    const int p = blockIdx.x * 256 + t;       // NPAIRS == 12500*256
    if (t == 0) nheads = 0;

    float x[14];
    {
        const float2* pr2 = (const float2*)(pf + (size_t)p * 14);
#pragma unroll
        for (int k = 0; k < 7; ++k) {
            float2 v = pr2[k];
            x[2 * k] = v.x; x[2 * k + 1] = v.y;
        }
    }
    ps_lds[t] = psplit[p];

    // PA = relu(pf@W_PA.T + b_PA) -> packed bf16 LDS, row-dot form (2 rows/iter)
#pragma unroll 1
    for (int u = 0; u < 25; ++u) {
        const int j = 2 * u;
        const float2* w0 = (const float2*)(W_PA + (size_t)j * 14);
        const float2* w1 = (const float2*)(W_PA + (size_t)(j + 1) * 14);
        float a0 = b_PA[j], a1 = b_PA[j + 1];
#pragma unroll
        for (int k = 0; k < 7; ++k) {
            float2 wa = w0[k], wb = w1[k];
            a0 = fmaf(x[2 * k], wa.x, a0); a0 = fmaf(x[2 * k + 1], wa.y, a0);
            a1 = fmaf(x[2 * k], wb.x, a1); a1 = fmaf(x[2 * k + 1], wb.y, a1);
        }
        pa_lds[t * 27 + u] = pack2(fmaxf(a0, 0.0f), fmaxf(a1, 0.0f));
    }

    // S via bf16 gather: s[f] = relu(X1'_i[f]+X2_j[f]) + relu(X1'_j[f]+X2_i[f])
    float s[50];
    {
        const int2 ij = ((const int2*)a2p)[p];
        const uint4* xi4 = (const uint4*)(XAu + (size_t)ij.x * 56);
        const uint4* xj4 = (const uint4*)(XAu + (size_t)ij.y * 56);
#pragma unroll
        for (int c = 0; c < 6; ++c) {
            uint4 A = xi4[c];       // X1'_i elems 8c..8c+7
            uint4 B = xj4[7 + c];   // X2_j
            uint4 C = xj4[c];       // X1'_j
            uint4 D = xi4[7 + c];   // X2_i
            s[8 * c + 0] = fmaxf(bflo(A.x) + bflo(B.x), 0.f) + fmaxf(bflo(C.x) + bflo(D.x), 0.f);
            s[8 * c + 1] = fmaxf(bfhi(A.x) + bfhi(B.x), 0.f) + fmaxf(bfhi(C.x) + bfhi(D.x), 0.f);
            s[8 * c + 2] = fmaxf(bflo(A.y) + bflo(B.y), 0.f) + fmaxf(bflo(C.y) + bflo(D.y), 0.f);
            s[8 * c + 3] = fmaxf(bfhi(A.y) + bfhi(B.y), 0.f) + fmaxf(bfhi(C.y) + bfhi(D.y), 0.f);
            s[8 * c + 4] = fmaxf(bflo(A.z) + bflo(B.z), 0.f) + fmaxf(bflo(C.z) + bflo(D.z), 0.f);
            s[8 * c + 5] = fmaxf(bfhi(A.z) + bfhi(B.z), 0.f) + fmaxf(bfhi(C.z) + bfhi(D.z), 0.f);
            s[8 * c + 6] = fmaxf(bflo(A.w) + bflo(B.w), 0.f) + fmaxf(bflo(C.w) + bflo(D.w), 0.f);
            s[8 * c + 7] = fmaxf(bfhi(A.w) + bfhi(B.w), 0.f) + fmaxf(bfhi(C.w) + bfhi(D.w), 0.f);
        }
        const unsigned int* xiu = XAu + (size_t)ij.x * 56;
        const unsigned int* xju = XAu + (size_t)ij.y * 56;
        unsigned int A = xiu[24], B = xju[52], C = xju[24], D = xiu[52];
        s[48] = fmaxf(bflo(A) + bflo(B), 0.f) + fmaxf(bflo(C) + bflo(D), 0.f);
        s[49] = fmaxf(bfhi(A) + bfhi(B), 0.f) + fmaxf(bfhi(C) + bfhi(D), 0.f);
    }

    // PP = relu(pf@W_PP.T + b_PP); FULL unroll (pp[] must stay in registers)
    float pp[50];
#pragma unroll
    for (int u = 0; u < 25; ++u) {
        const int j = 2 * u;
        const float2* w0 = (const float2*)(W_PP + (size_t)j * 14);
        const float2* w1 = (const float2*)(W_PP + (size_t)(j + 1) * 14);
        float a0 = b_PP[j], a1 = b_PP[j + 1];
#pragma unroll
        for (int k = 0; k < 7; ++k) {
            float2 wa = w0[k], wb = w1[k];
            a0 = fmaf(x[2 * k], wa.x, a0); a0 = fmaf(x[2 * k + 1], wa.y, a0);
            a1 = fmaf(x[2 * k], wb.x, a1); a1 = fmaf(x[2 * k + 1], wb.y, a1);
        }
        pp[j]     = fmaxf(a0, 0.0f);
        pp[j + 1] = fmaxf(a1, 0.0f);
    }

    // P[o] = relu(b_P[o] + [s,pp] . W_P_row(o)) — per-output dot, W row via float4
    float* po = Pout + (size_t)p * 50;
#pragma unroll 2
    for (int o = 0; o < 50; ++o) {
        const float4* w4 = (const float4*)(W_P + (size_t)o * 100);  // 400B stride, 16B aligned
        float acc = b_P[o];
#pragma unroll
        for (int q = 0; q < 25; ++q) {
            float4 w = w4[q];
            const int f = 4 * q;
            const float v0 = (f + 0 < 50) ? s[f + 0] : pp[f + 0 - 50];
            const float v1 = (f + 1 < 50) ? s[f + 1] : pp[f + 1 - 50];
            const float v2 = (f + 2 < 50) ? s[f + 2] : pp[f + 2 - 50];
            const float v3 = (f + 3 < 50) ? s[f + 3] : pp[f + 3 - 50];
            acc = fmaf(v0, w.x, acc);
            acc = fmaf(v1, w.y, acc);
            acc = fmaf(v2, w.z, acc);
            acc = fmaf(v3, w.w, acc);
        }
        po[o] = fmaxf(acc, 0.0f);
    }

    // segment-sum of PA (pair_split sorted): per-block run reduction + atomics
    __syncthreads();
    bool head = (t == 0) || (ps_lds[t] != ps_lds[t - 1]);
    if (head) {
        int idx = atomicAdd(&nheads, 1);
        head_list[idx] = t;
    }
    __syncthreads();

    const int nh = nheads;
    for (int w = t; w < nh * 25; w += 256) {
        const int r0  = head_list[w / 25];
        const int jc  = w % 25;
        const int seg = ps_lds[r0];
        float a0 = 0.0f, a1 = 0.0f;
        int rr = r0;
        do {
            unsigned int u = pa_lds[rr * 27 + jc];
            a0 += bflo(u);
            a1 += bfhi(u);
            ++rr;
        } while (rr < 256 && ps_lds[rr] == seg);
        atomicAdd(&PAsum[(size_t)seg * 50 + 2 * jc],     a0);
        atomicAdd(&PAsum[(size_t)seg * 50 + 2 * jc + 1], a1);
    }
}

// K3: A = relu(concat(AA, PAsum) @ W_A.T + b_A). blockIdx.y picks output half.
__global__ __launch_bounds__(256, 2) void k_atom_final(
    const float* __restrict__ AA, const float* __restrict__ PAsum,
    const float* __restrict__ W_A, const float* __restrict__ b_A,
    float* __restrict__ Aout)
{
    const int a = blockIdx.x * 256 + threadIdx.x;
    if (a >= NATOMS) return;
    const int o0 = blockIdx.y * 25;

    float v[100];
    {
        const float2* p1 = (const float2*)(AA + (size_t)a * 50);
        const float2* p2 = (const float2*)(PAsum + (size_t)a * 50);
#pragma unroll
        for (int q = 0; q < 25; ++q) {
            float2 u1 = p1[q], u2 = p2[q];
            v[2 * q] = u1.x;      v[2 * q + 1] = u1.y;
            v[50 + 2 * q] = u2.x; v[50 + 2 * q + 1] = u2.y;
        }
    }
    float* ao = Aout + (size_t)a * 50;
#pragma unroll 2
    for (int o = o0; o < o0 + 25; ++o) {
        const float4* w4 = (const float4*)(W_A + (size_t)o * 100);
        float acc = b_A[o];
#pragma unroll
        for (int q = 0; q < 25; ++q) {
            float4 w = w4[q];
            acc = fmaf(v[4 * q + 0], w.x, acc);
            acc = fmaf(v[4 * q + 1], w.y, acc);
            acc = fmaf(v[4 * q + 2], w.z, acc);
            acc = fmaf(v[4 * q + 3], w.w, acc);
        }
        ao[o] = fmaxf(acc, 0.0f);
    }
}

extern "C" void kernel_launch(void* const* d_in, const int* in_sizes, int n_in,
                              void* d_out, int out_size, void* d_ws, size_t ws_size,
                              hipStream_t stream)
{
    const float* atom_features = (const float*)d_in[0];
    const float* pair_features = (const float*)d_in[1];
    const int*   pair_split    = (const int*)d_in[2];
    const int*   atom_to_pair  = (const int*)d_in[3];
    const float* W_AA = (const float*)d_in[4];
    const float* b_AA = (const float*)d_in[5];
    const float* W_PA = (const float*)d_in[6];
    const float* b_PA = (const float*)d_in[7];
    const float* W_A  = (const float*)d_in[8];
    const float* b_A  = (const float*)d_in[9];
    const float* W_AP = (const float*)d_in[10];
    const float* b_AP = (const float*)d_in[11];
    const float* W_PP = (const float*)d_in[12];
    const float* b_PP = (const float*)d_in[13];
    const float* W_P  = (const float*)d_in[14];
    const float* b_P  = (const float*)d_in[15];

    float* out   = (float*)d_out;
    float* A_out = out;                              // [NATOMS,50]
    float* P_out = out + (size_t)NATOMS * 50;        // [NPAIRS,50]

    float*        AA    = (float*)d_ws;                               // 5,000,000 f32
    unsigned int* XAu   = (unsigned int*)(AA + (size_t)NATOMS * 50);  // 5,600,000 u32
    float*        PAsum = (float*)(XAu + (size_t)NATOMS * 56);        // 5,000,000 f32

    hipMemsetAsync(PAsum, 0, (size_t)NATOMS * 50 * sizeof(float), stream);

    k_atom_pre<<<dim3(391, 2), 256, 0, stream>>>(
        atom_features, W_AA, b_AA, W_AP, b_AP, AA, XAu);

    k_pair<<<NPAIRS / 256, 256, 0, stream>>>(
        pair_features, pair_split, atom_to_pair,
        W_PA, b_PA, W_PP, b_PP, W_P, b_P,
        XAu, PAsum, P_out);

    k_atom_final<<<dim3(391, 2), 256, 0, stream>>>(
        AA, PAsum, W_A, b_A, A_out);
}

// Round 5
// 2112.144 us; speedup vs baseline: 4.8763x; 1.1275x over previous
//
#include <hip/hip_runtime.h>

#define NATOMS 100000
#define NPAIRS 3200000
// F_ATOM=75, F_PAIR=14, H=50, F_OUT=50

__device__ __forceinline__ unsigned short f2bf(float f) {
    unsigned int u = __float_as_uint(f);
    unsigned int r = (u + 0x7fffu + ((u >> 16) & 1u)) >> 16;   // RNE
    return (unsigned short)r;
}
__device__ __forceinline__ float bflo(unsigned int u) { return __uint_as_float(u << 16); }
__device__ __forceinline__ float bfhi(unsigned int u) { return __uint_as_float(u & 0xffff0000u); }
__device__ __forceinline__ unsigned int pack2(float a, float b) {
    return (unsigned int)f2bf(a) | ((unsigned int)f2bf(b) << 16);
}

// XA row layout (uints, stride 56 per atom = 224 B, 16B aligned):
//   uints 0..24  : X1' = af@W_AP[:, :75].T + b_AP   (pair-packed bf16)
//   uints 28..52 : X2  = af@W_AP[:, 75:].T
// (uints 25..27, 53..55 pad)

// K1: per-atom precompute. blockIdx.y = half so weight rows stay wave-uniform.
__global__ __launch_bounds__(256, 2) void k_atom_pre(
    const float* __restrict__ af,
    const float* __restrict__ W_AA, const float* __restrict__ b_AA,
    const float* __restrict__ W_AP, const float* __restrict__ b_AP,
    float* __restrict__ AA, unsigned int* __restrict__ XAu)
{
    const int a = blockIdx.x * 256 + threadIdx.x;
    if (a >= NATOMS) return;
    const int half = blockIdx.y;

    const float* ar = af + (size_t)a * 75;
    float x[75];
#pragma unroll
    for (int k = 0; k < 75; ++k) x[k] = ar[k];

    const int jbase = half ? 26 : 0;
    const int jend  = half ? 50 : 26;

    float* aout = AA + (size_t)a * 50;
#pragma unroll 2
    for (int j = jbase; j < jend; ++j) {
        const float* wr = W_AA + (size_t)j * 75;
        float acc = b_AA[j];
#pragma unroll
        for (int k = 0; k < 75; ++k) acc = fmaf(x[k], wr[k], acc);
        aout[j] = fmaxf(acc, 0.0f);
    }

    unsigned int* xout = XAu + (size_t)a * 56;
    const int nu    = half ? 12 : 13;
    const int ubase = half ? 13 : 0;
#pragma unroll 1
    for (int u = 0; u < nu; ++u) {
        const int j = jbase + 2 * u;
        const float2* w0 = (const float2*)(W_AP + (size_t)j * 150);
        const float2* w1 = (const float2*)(W_AP + (size_t)(j + 1) * 150);
        float a0 = b_AP[j], a1 = b_AP[j + 1];
        float c0 = 0.0f,   c1 = 0.0f;
#pragma unroll
        for (int q = 0; q < 37; ++q) {
            float2 wa = w0[q], wb = w1[q];
            a0 = fmaf(x[2 * q], wa.x, a0); a0 = fmaf(x[2 * q + 1], wa.y, a0);
            a1 = fmaf(x[2 * q], wb.x, a1); a1 = fmaf(x[2 * q + 1], wb.y, a1);
        }
        a0 = fmaf(x[74], ((const float*)w0)[74], a0);
        a1 = fmaf(x[74], ((const float*)w1)[74], a1);
        c0 = fmaf(x[0], ((const float*)w0)[75], c0);
        c1 = fmaf(x[0], ((const float*)w1)[75], c1);
#pragma unroll
        for (int q = 0; q < 37; ++q) {
            float2 wa = ((const float2*)(((const float*)w0) + 76))[q];
            float2 wb = ((const float2*)(((const float*)w1) + 76))[q];
            c0 = fmaf(x[2 * q + 1], wa.x, c0); c0 = fmaf(x[2 * q + 2], wa.y, c0);
            c1 = fmaf(x[2 * q + 1], wb.x, c1); c1 = fmaf(x[2 * q + 2], wb.y, c1);
        }
        xout[ubase + u]      = pack2(a0, a1);
        xout[28 + ubase + u] = pack2(c0, c1);
    }
}

// K2: per-pair fused kernel. Chunked-K accumulation: only acc[50] is a large
// live array (~90 regs peak) so the allocator's waves-target can't force spills.
__global__ __launch_bounds__(256, 4) void k_pair(
    const float* __restrict__ pf,
    const int* __restrict__ psplit,
    const int* __restrict__ a2p,
    const float* __restrict__ W_PA, const float* __restrict__ b_PA,
    const float* __restrict__ W_PP, const float* __restrict__ b_PP,
    const float* __restrict__ W_P,  const float* __restrict__ b_P,
    const unsigned int* __restrict__ XAu,
    float* __restrict__ PAsum,
    float* __restrict__ Pout)
{
    __shared__ unsigned int pa_lds[256 * 27];  // stride 27 (odd)
    __shared__ int head_list[256];
    __shared__ int ps_lds[256];
    __shared__ int nheads;

    const int t = threadIdx.x;
    const int p = blockIdx.x * 256 + t;       // NPAIRS == 12500*256
    if (t == 0) nheads = 0;

    float x[14];
    {
        const float2* pr2 = (const float2*)(pf + (size_t)p * 14);
#pragma unroll
        for (int k = 0; k < 7; ++k) {
            float2 v = pr2[k];
            x[2 * k] = v.x; x[2 * k + 1] = v.y;
        }
    }
    ps_lds[t] = psplit[p];

    // PA = relu(pf@W_PA.T + b_PA) -> packed bf16 LDS, 2 rows/iter
#pragma unroll 1
    for (int u = 0; u < 25; ++u) {
        const int j = 2 * u;
        const float2* w0 = (const float2*)(W_PA + (size_t)j * 14);
        const float2* w1 = (const float2*)(W_PA + (size_t)(j + 1) * 14);
        float a0 = b_PA[j], a1 = b_PA[j + 1];
#pragma unroll
        for (int k = 0; k < 7; ++k) {
            float2 wa = w0[k], wb = w1[k];
            a0 = fmaf(x[2 * k], wa.x, a0); a0 = fmaf(x[2 * k + 1], wa.y, a0);
            a1 = fmaf(x[2 * k], wb.x, a1); a1 = fmaf(x[2 * k + 1], wb.y, a1);
        }
        pa_lds[t * 27 + u] = pack2(fmaxf(a0, 0.0f), fmaxf(a1, 0.0f));
    }

    // acc[50] = b_P; stream K through it.
    float acc[50];
#pragma unroll
    for (int o = 0; o < 50; ++o) acc[o] = b_P[o];

    // Phase A: gather chunks of 8 s-values, FMA into acc[0..49] immediately.
    // Weights W_P[o][f] are wave-uniform compile-time offsets -> s_load broadcast.
    {
        const int2 ij = ((const int2*)a2p)[p];
        const uint4* xi4 = (const uint4*)(XAu + (size_t)ij.x * 56);
        const uint4* xj4 = (const uint4*)(XAu + (size_t)ij.y * 56);
#pragma unroll 2
        for (int c = 0; c < 6; ++c) {
            uint4 A = xi4[c];       // X1'_i elems 8c..8c+7
            uint4 B = xj4[7 + c];   // X2_j
            uint4 C = xj4[c];       // X1'_j
            uint4 D = xi4[7 + c];   // X2_i
            float s8[8];
            s8[0] = fmaxf(bflo(A.x) + bflo(B.x), 0.f) + fmaxf(bflo(C.x) + bflo(D.x), 0.f);
            s8[1] = fmaxf(bfhi(A.x) + bfhi(B.x), 0.f) + fmaxf(bfhi(C.x) + bfhi(D.x), 0.f);
            s8[2] = fmaxf(bflo(A.y) + bflo(B.y), 0.f) + fmaxf(bflo(C.y) + bflo(D.y), 0.f);
            s8[3] = fmaxf(bfhi(A.y) + bfhi(B.y), 0.f) + fmaxf(bfhi(C.y) + bfhi(D.y), 0.f);
            s8[4] = fmaxf(bflo(A.z) + bflo(B.z), 0.f) + fmaxf(bflo(C.z) + bflo(D.z), 0.f);
            s8[5] = fmaxf(bfhi(A.z) + bfhi(B.z), 0.f) + fmaxf(bfhi(C.z) + bfhi(D.z), 0.f);
            s8[6] = fmaxf(bflo(A.w) + bflo(B.w), 0.f) + fmaxf(bflo(C.w) + bflo(D.w), 0.f);
            s8[7] = fmaxf(bfhi(A.w) + bfhi(B.w), 0.f) + fmaxf(bfhi(C.w) + bfhi(D.w), 0.f);
#pragma unroll
            for (int o = 0; o < 50; ++o) {
                const float* wr = W_P + (size_t)o * 100 + 8 * c;
                acc[o] = fmaf(s8[0], wr[0], acc[o]);
                acc[o] = fmaf(s8[1], wr[1], acc[o]);
                acc[o] = fmaf(s8[2], wr[2], acc[o]);
                acc[o] = fmaf(s8[3], wr[3], acc[o]);
                acc[o] = fmaf(s8[4], wr[4], acc[o]);
                acc[o] = fmaf(s8[5], wr[5], acc[o]);
                acc[o] = fmaf(s8[6], wr[6], acc[o]);
                acc[o] = fmaf(s8[7], wr[7], acc[o]);
            }
        }
        // tail f=48,49
        const unsigned int* xiu = XAu + (size_t)ij.x * 56;
        const unsigned int* xju = XAu + (size_t)ij.y * 56;
        unsigned int A = xiu[24], B = xju[52], C = xju[24], D = xiu[52];
        float s48 = fmaxf(bflo(A) + bflo(B), 0.f) + fmaxf(bflo(C) + bflo(D), 0.f);
        float s49 = fmaxf(bfhi(A) + bfhi(B), 0.f) + fmaxf(bfhi(C) + bfhi(D), 0.f);
#pragma unroll
        for (int o = 0; o < 50; ++o) {
            const float* wr = W_P + (size_t)o * 100 + 48;
            acc[o] = fmaf(s48, wr[0], acc[o]);
            acc[o] = fmaf(s49, wr[1], acc[o]);
        }
    }

    // Phase B: pp two values at a time, FMA into acc. pp never materialized.
#pragma unroll 1
    for (int u = 0; u < 25; ++u) {
        const int j = 2 * u;
        const float2* w0 = (const float2*)(W_PP + (size_t)j * 14);
        const float2* w1 = (const float2*)(W_PP + (size_t)(j + 1) * 14);
        float a0 = b_PP[j], a1 = b_PP[j + 1];
#pragma unroll
        for (int k = 0; k < 7; ++k) {
            float2 wa = w0[k], wb = w1[k];
            a0 = fmaf(x[2 * k], wa.x, a0); a0 = fmaf(x[2 * k + 1], wa.y, a0);
            a1 = fmaf(x[2 * k], wb.x, a1); a1 = fmaf(x[2 * k + 1], wb.y, a1);
        }
        a0 = fmaxf(a0, 0.0f);
        a1 = fmaxf(a1, 0.0f);
#pragma unroll
        for (int o = 0; o < 50; ++o) {
            const float2 w = *(const float2*)(W_P + (size_t)o * 100 + 50 + j);  // 8B aligned (j even)
            acc[o] = fmaf(a0, w.x, acc[o]);
            acc[o] = fmaf(a1, w.y, acc[o]);
        }
    }

    // store P row (8B-aligned) as float2
    {
        float2* po2 = (float2*)(Pout + (size_t)p * 50);
#pragma unroll
        for (int q = 0; q < 25; ++q) {
            float2 v;
            v.x = fmaxf(acc[2 * q],     0.0f);
            v.y = fmaxf(acc[2 * q + 1], 0.0f);
            po2[q] = v;
        }
    }

    // segment-sum of PA (pair_split sorted): per-block run reduction + atomics
    __syncthreads();
    bool head = (t == 0) || (ps_lds[t] != ps_lds[t - 1]);
    if (head) {
        int idx = atomicAdd(&nheads, 1);
        head_list[idx] = t;
    }
    __syncthreads();

    const int nh = nheads;
    for (int w = t; w < nh * 25; w += 256) {
        const int r0  = head_list[w / 25];
        const int jc  = w % 25;
        const int seg = ps_lds[r0];
        float a0 = 0.0f, a1 = 0.0f;
        int rr = r0;
        do {
            unsigned int u = pa_lds[rr * 27 + jc];
            a0 += bflo(u);
            a1 += bfhi(u);
            ++rr;
        } while (rr < 256 && ps_lds[rr] == seg);
        atomicAdd(&PAsum[(size_t)seg * 50 + 2 * jc],     a0);
        atomicAdd(&PAsum[(size_t)seg * 50 + 2 * jc + 1], a1);
    }
}

// K3: A = relu(concat(AA, PAsum) @ W_A.T + b_A). blockIdx.y picks output half.
__global__ __launch_bounds__(256, 2) void k_atom_final(
    const float* __restrict__ AA, const float* __restrict__ PAsum,
    const float* __restrict__ W_A, const float* __restrict__ b_A,
    float* __restrict__ Aout)
{
    const int a = blockIdx.x * 256 + threadIdx.x;
    if (a >= NATOMS) return;
    const int o0 = blockIdx.y * 25;

    float v[100];
    {
        const float2* p1 = (const float2*)(AA + (size_t)a * 50);
        const float2* p2 = (const float2*)(PAsum + (size_t)a * 50);
#pragma unroll
        for (int q = 0; q < 25; ++q) {
            float2 u1 = p1[q], u2 = p2[q];
            v[2 * q] = u1.x;      v[2 * q + 1] = u1.y;
            v[50 + 2 * q] = u2.x; v[50 + 2 * q + 1] = u2.y;
        }
    }
    float* ao = Aout + (size_t)a * 50;
#pragma unroll 2
    for (int o = o0; o < o0 + 25; ++o) {
        const float4* w4 = (const float4*)(W_A + (size_t)o * 100);
        float acc = b_A[o];
#pragma unroll
        for (int q = 0; q < 25; ++q) {
            float4 w = w4[q];
            acc = fmaf(v[4 * q + 0], w.x, acc);
            acc = fmaf(v[4 * q + 1], w.y, acc);
            acc = fmaf(v[4 * q + 2], w.z, acc);
            acc = fmaf(v[4 * q + 3], w.w, acc);
        }
        ao[o] = fmaxf(acc, 0.0f);
    }
}

extern "C" void kernel_launch(void* const* d_in, const int* in_sizes, int n_in,
                              void* d_out, int out_size, void* d_ws, size_t ws_size,
                              hipStream_t stream)
{
    const float* atom_features = (const float*)d_in[0];
    const float* pair_features = (const float*)d_in[1];
    const int*   pair_split    = (const int*)d_in[2];
    const int*   atom_to_pair  = (const int*)d_in[3];
    const float* W_AA = (const float*)d_in[4];
    const float* b_AA = (const float*)d_in[5];
    const float* W_PA = (const float*)d_in[6];
    const float* b_PA = (const float*)d_in[7];
    const float* W_A  = (const float*)d_in[8];
    const float* b_A  = (const float*)d_in[9];
    const float* W_AP = (const float*)d_in[10];
    const float* b_AP = (const float*)d_in[11];
    const float* W_PP = (const float*)d_in[12];
    const float* b_PP = (const float*)d_in[13];
    const float* W_P  = (const float*)d_in[14];
    const float* b_P  = (const float*)d_in[15];

    float* out   = (float*)d_out;
    float* A_out = out;                              // [NATOMS,50]
    float* P_out = out + (size_t)NATOMS * 50;        // [NPAIRS,50]

    float*        AA    = (float*)d_ws;                               // 5,000,000 f32
    unsigned int* XAu   = (unsigned int*)(AA + (size_t)NATOMS * 50);  // 5,600,000 u32
    float*        PAsum = (float*)(XAu + (size_t)NATOMS * 56);        // 5,000,000 f32

    hipMemsetAsync(PAsum, 0, (size_t)NATOMS * 50 * sizeof(float), stream);

    k_atom_pre<<<dim3(391, 2), 256, 0, stream>>>(
        atom_features, W_AA, b_AA, W_AP, b_AP, AA, XAu);

    k_pair<<<NPAIRS / 256, 256, 0, stream>>>(
        pair_features, pair_split, atom_to_pair,
        W_PA, b_PA, W_PP, b_PP, W_P, b_P,
        XAu, PAsum, P_out);

    k_atom_final<<<dim3(391, 2), 256, 0, stream>>>(
        AA, PAsum, W_A, b_A, A_out);
}

// Round 6
// 1963.407 us; speedup vs baseline: 5.2457x; 1.0758x over previous
//
#include <hip/hip_runtime.h>

#define NATOMS 100000
#define NPAIRS 3200000
// F_ATOM=75, F_PAIR=14, H=50, F_OUT=50

__device__ __forceinline__ unsigned short f2bf(float f) {
    unsigned int u = __float_as_uint(f);
    unsigned int r = (u + 0x7fffu + ((u >> 16) & 1u)) >> 16;   // RNE
    return (unsigned short)r;
}
__device__ __forceinline__ float bflo(unsigned int u) { return __uint_as_float(u << 16); }
__device__ __forceinline__ float bfhi(unsigned int u) { return __uint_as_float(u & 0xffff0000u); }
__device__ __forceinline__ unsigned int pack2(float a, float b) {
    return (unsigned int)f2bf(a) | ((unsigned int)f2bf(b) << 16);
}

// XA row layout (uints, stride 56 per atom = 224 B, 16B aligned):
//   uints 0..24  : X1' = af@W_AP[:, :75].T + b_AP   (pair-packed bf16)
//   uints 28..52 : X2  = af@W_AP[:, 75:].T
// (uints 25..27, 53..55 pad)

// K1: per-atom precompute. blockIdx.y = half so weight rows stay wave-uniform.
__global__ __launch_bounds__(256, 2) void k_atom_pre(
    const float* __restrict__ af,
    const float* __restrict__ W_AA, const float* __restrict__ b_AA,
    const float* __restrict__ W_AP, const float* __restrict__ b_AP,
    float* __restrict__ AA, unsigned int* __restrict__ XAu)
{
    const int a = blockIdx.x * 256 + threadIdx.x;
    if (a >= NATOMS) return;
    const int half = blockIdx.y;

    const float* ar = af + (size_t)a * 75;
    float x[75];
#pragma unroll
    for (int k = 0; k < 75; ++k) x[k] = ar[k];

    const int jbase = half ? 26 : 0;
    const int jend  = half ? 50 : 26;

    float* aout = AA + (size_t)a * 50;
#pragma unroll 2
    for (int j = jbase; j < jend; ++j) {
        const float* wr = W_AA + (size_t)j * 75;
        float acc = b_AA[j];
#pragma unroll
        for (int k = 0; k < 75; ++k) acc = fmaf(x[k], wr[k], acc);
        aout[j] = fmaxf(acc, 0.0f);
    }

    unsigned int* xout = XAu + (size_t)a * 56;
    const int nu    = half ? 12 : 13;
    const int ubase = half ? 13 : 0;
#pragma unroll 1
    for (int u = 0; u < nu; ++u) {
        const int j = jbase + 2 * u;
        const float2* w0 = (const float2*)(W_AP + (size_t)j * 150);
        const float2* w1 = (const float2*)(W_AP + (size_t)(j + 1) * 150);
        float a0 = b_AP[j], a1 = b_AP[j + 1];
        float c0 = 0.0f,   c1 = 0.0f;
#pragma unroll
        for (int q = 0; q < 37; ++q) {
            float2 wa = w0[q], wb = w1[q];
            a0 = fmaf(x[2 * q], wa.x, a0); a0 = fmaf(x[2 * q + 1], wa.y, a0);
            a1 = fmaf(x[2 * q], wb.x, a1); a1 = fmaf(x[2 * q + 1], wb.y, a1);
        }
        a0 = fmaf(x[74], ((const float*)w0)[74], a0);
        a1 = fmaf(x[74], ((const float*)w1)[74], a1);
        c0 = fmaf(x[0], ((const float*)w0)[75], c0);
        c1 = fmaf(x[0], ((const float*)w1)[75], c1);
#pragma unroll
        for (int q = 0; q < 37; ++q) {
            float2 wa = ((const float2*)(((const float*)w0) + 76))[q];
            float2 wb = ((const float2*)(((const float*)w1) + 76))[q];
            c0 = fmaf(x[2 * q + 1], wa.x, c0); c0 = fmaf(x[2 * q + 2], wa.y, c0);
            c1 = fmaf(x[2 * q + 1], wb.x, c1); c1 = fmaf(x[2 * q + 2], wb.y, c1);
        }
        xout[ubase + u]      = pack2(a0, a1);
        xout[28 + ubase + u] = pack2(c0, c1);
    }
}

// K2: per-pair fused kernel. 4 waves/block; wave pair {half=0, half=1} shares
// 64 pairs, each wave computes 25 of the 50 P-outputs. Live set ~58 VGPRs so
// the allocator's 64-reg/8-wave occupancy tier fits with NO spill.
// `half` goes through readfirstlane so weight addresses stay SGPR (s_load).
__global__ __launch_bounds__(256, 4) void k_pair(
    const float* __restrict__ pf,
    const int* __restrict__ psplit,
    const int* __restrict__ a2p,
    const float* __restrict__ W_PA, const float* __restrict__ b_PA,
    const float* __restrict__ W_PP, const float* __restrict__ b_PP,
    const float* __restrict__ W_P,  const float* __restrict__ b_P,
    const unsigned int* __restrict__ XAu,
    float* __restrict__ PAsum,
    float* __restrict__ Pout)
{
    __shared__ unsigned int pa_lds[128 * 27];  // 25 used/row, stride 27 (odd)
    __shared__ int head_list[128];
    __shared__ int ps_lds[128];
    __shared__ int nheads;

    const int t    = threadIdx.x;
    const int lane = t & 63;
    const int half = __builtin_amdgcn_readfirstlane((t >> 6) & 1);  // wave-uniform -> SGPR
    const int pg   = t >> 7;                   // pair-group 0/1
    const int pr   = pg * 64 + lane;           // pair-in-block 0..127
    const int p    = blockIdx.x * 128 + pr;    // NPAIRS == 25000*128
    const int o0   = half * 25;                // scalar output base

    if (t == 0) nheads = 0;
    if (t < 128) ps_lds[t] = psplit[blockIdx.x * 128 + t];

    float x[14];
    {
        const float2* pr2 = (const float2*)(pf + (size_t)p * 14);
#pragma unroll
        for (int k = 0; k < 7; ++k) {
            float2 v = pr2[k];
            x[2 * k] = v.x; x[2 * k + 1] = v.y;
        }
    }

    // PA rows split by half: half0 -> uints 0..12 (rows 0..25), half1 -> 13..24 (rows 26..49)
    {
        const int ub = half ? 13 : 0;
        const int ue = half ? 25 : 13;
#pragma unroll 1
        for (int u = ub; u < ue; ++u) {
            const int j = 2 * u;
            const float2* w0 = (const float2*)(W_PA + (size_t)j * 14);
            const float2* w1 = (const float2*)(W_PA + (size_t)(j + 1) * 14);
            float a0 = b_PA[j], a1 = b_PA[j + 1];
#pragma unroll
            for (int k = 0; k < 7; ++k) {
                float2 wa = w0[k], wb = w1[k];
                a0 = fmaf(x[2 * k], wa.x, a0); a0 = fmaf(x[2 * k + 1], wa.y, a0);
                a1 = fmaf(x[2 * k], wb.x, a1); a1 = fmaf(x[2 * k + 1], wb.y, a1);
            }
            pa_lds[pr * 27 + u] = pack2(fmaxf(a0, 0.0f), fmaxf(a1, 0.0f));
        }
    }

    // acc[25] = b_P[o0..o0+24]
    float acc[25];
#pragma unroll
    for (int o = 0; o < 25; ++o) acc[o] = b_P[o0 + o];

    // Phase B: pp streamed two at a time (x dies after this phase)
#pragma unroll 1
    for (int u = 0; u < 25; ++u) {
        const int j = 2 * u;
        const float2* w0 = (const float2*)(W_PP + (size_t)j * 14);
        const float2* w1 = (const float2*)(W_PP + (size_t)(j + 1) * 14);
        float a0 = b_PP[j], a1 = b_PP[j + 1];
#pragma unroll
        for (int k = 0; k < 7; ++k) {
            float2 wa = w0[k], wb = w1[k];
            a0 = fmaf(x[2 * k], wa.x, a0); a0 = fmaf(x[2 * k + 1], wa.y, a0);
            a1 = fmaf(x[2 * k], wb.x, a1); a1 = fmaf(x[2 * k + 1], wb.y, a1);
        }
        a0 = fmaxf(a0, 0.0f);
        a1 = fmaxf(a1, 0.0f);
#pragma unroll
        for (int o = 0; o < 25; ++o) {
            const float2 w = *(const float2*)(W_P + (size_t)(o0 + o) * 100 + 50 + j);
            acc[o] = fmaf(a0, w.x, acc[o]);
            acc[o] = fmaf(a1, w.y, acc[o]);
        }
    }

    // Phase A: gather chunks of 8 s-values, FMA into acc immediately.
    {
        const int2 ij = ((const int2*)a2p)[p];
        const uint4* xi4 = (const uint4*)(XAu + (size_t)ij.x * 56);
        const uint4* xj4 = (const uint4*)(XAu + (size_t)ij.y * 56);
#pragma unroll 1
        for (int c = 0; c < 6; ++c) {
            uint4 A = xi4[c];       // X1'_i elems 8c..8c+7
            uint4 B = xj4[7 + c];   // X2_j
            uint4 C = xj4[c];       // X1'_j
            uint4 D = xi4[7 + c];   // X2_i
            float s8[8];
            s8[0] = fmaxf(bflo(A.x) + bflo(B.x), 0.f) + fmaxf(bflo(C.x) + bflo(D.x), 0.f);
            s8[1] = fmaxf(bfhi(A.x) + bfhi(B.x), 0.f) + fmaxf(bfhi(C.x) + bfhi(D.x), 0.f);
            s8[2] = fmaxf(bflo(A.y) + bflo(B.y), 0.f) + fmaxf(bflo(C.y) + bflo(D.y), 0.f);
            s8[3] = fmaxf(bfhi(A.y) + bfhi(B.y), 0.f) + fmaxf(bfhi(C.y) + bfhi(D.y), 0.f);
            s8[4] = fmaxf(bflo(A.z) + bflo(B.z), 0.f) + fmaxf(bflo(C.z) + bflo(D.z), 0.f);
            s8[5] = fmaxf(bfhi(A.z) + bfhi(B.z), 0.f) + fmaxf(bfhi(C.z) + bfhi(D.z), 0.f);
            s8[6] = fmaxf(bflo(A.w) + bflo(B.w), 0.f) + fmaxf(bflo(C.w) + bflo(D.w), 0.f);
            s8[7] = fmaxf(bfhi(A.w) + bfhi(B.w), 0.f) + fmaxf(bfhi(C.w) + bfhi(D.w), 0.f);
#pragma unroll
            for (int o = 0; o < 25; ++o) {
                const float* wr = W_P + (size_t)(o0 + o) * 100 + 8 * c;
                acc[o] = fmaf(s8[0], wr[0], acc[o]);
                acc[o] = fmaf(s8[1], wr[1], acc[o]);
                acc[o] = fmaf(s8[2], wr[2], acc[o]);
                acc[o] = fmaf(s8[3], wr[3], acc[o]);
                acc[o] = fmaf(s8[4], wr[4], acc[o]);
                acc[o] = fmaf(s8[5], wr[5], acc[o]);
                acc[o] = fmaf(s8[6], wr[6], acc[o]);
                acc[o] = fmaf(s8[7], wr[7], acc[o]);
            }
        }
        // tail f=48,49
        const unsigned int* xiu = (const unsigned int*)xi4;
        const unsigned int* xju = (const unsigned int*)xj4;
        unsigned int A = xiu[24], B = xju[52], C = xju[24], D = xiu[52];
        float s48 = fmaxf(bflo(A) + bflo(B), 0.f) + fmaxf(bflo(C) + bflo(D), 0.f);
        float s49 = fmaxf(bfhi(A) + bfhi(B), 0.f) + fmaxf(bfhi(C) + bfhi(D), 0.f);
#pragma unroll
        for (int o = 0; o < 25; ++o) {
            const float* wr = W_P + (size_t)(o0 + o) * 100 + 48;
            acc[o] = fmaf(s48, wr[0], acc[o]);
            acc[o] = fmaf(s49, wr[1], acc[o]);
        }
    }

    // store this half's 25 outputs
    {
        float* po = Pout + (size_t)p * 50 + o0;
#pragma unroll
        for (int o = 0; o < 25; ++o) po[o] = fmaxf(acc[o], 0.0f);
    }

    // segment-sum of PA (pair_split sorted): per-block run reduction + atomics
    __syncthreads();
    if (t < 128) {
        bool head = (t == 0) || (ps_lds[t] != ps_lds[t - 1]);
        if (head) {
            int idx = atomicAdd(&nheads, 1);
            head_list[idx] = t;
        }
    }
    __syncthreads();

    const int nh = nheads;
    for (int w = t; w < nh * 25; w += 256) {
        const int r0  = head_list[w / 25];
        const int jc  = w % 25;
        const int seg = ps_lds[r0];
        float a0 = 0.0f, a1 = 0.0f;
        int rr = r0;
        do {
            unsigned int u = pa_lds[rr * 27 + jc];
            a0 += bflo(u);
            a1 += bfhi(u);
            ++rr;
        } while (rr < 128 && ps_lds[rr] == seg);
        atomicAdd(&PAsum[(size_t)seg * 50 + 2 * jc],     a0);
        atomicAdd(&PAsum[(size_t)seg * 50 + 2 * jc + 1], a1);
    }
}

// K3: A = relu(concat(AA, PAsum) @ W_A.T + b_A). blockIdx.y picks output half.
__global__ __launch_bounds__(256, 2) void k_atom_final(
    const float* __restrict__ AA, const float* __restrict__ PAsum,
    const float* __restrict__ W_A, const float* __restrict__ b_A,
    float* __restrict__ Aout)
{
    const int a = blockIdx.x * 256 + threadIdx.x;
    if (a >= NATOMS) return;
    const int o0 = blockIdx.y * 25;

    float v[100];
    {
        const float2* p1 = (const float2*)(AA + (size_t)a * 50);
        const float2* p2 = (const float2*)(PAsum + (size_t)a * 50);
#pragma unroll
        for (int q = 0; q < 25; ++q) {
            float2 u1 = p1[q], u2 = p2[q];
            v[2 * q] = u1.x;      v[2 * q + 1] = u1.y;
            v[50 + 2 * q] = u2.x; v[50 + 2 * q + 1] = u2.y;
        }
    }
    float* ao = Aout + (size_t)a * 50;
#pragma unroll 2
    for (int o = o0; o < o0 + 25; ++o) {
        const float4* w4 = (const float4*)(W_A + (size_t)o * 100);
        float acc = b_A[o];
#pragma unroll
        for (int q = 0; q < 25; ++q) {
            float4 w = w4[q];
            acc = fmaf(v[4 * q + 0], w.x, acc);
            acc = fmaf(v[4 * q + 1], w.y, acc);
            acc = fmaf(v[4 * q + 2], w.z, acc);
            acc = fmaf(v[4 * q + 3], w.w, acc);
        }
        ao[o] = fmaxf(acc, 0.0f);
    }
}

extern "C" void kernel_launch(void* const* d_in, const int* in_sizes, int n_in,
                              void* d_out, int out_size, void* d_ws, size_t ws_size,
                              hipStream_t stream)
{
    const float* atom_features = (const float*)d_in[0];
    const float* pair_features = (const float*)d_in[1];
    const int*   pair_split    = (const int*)d_in[2];
    const int*   atom_to_pair  = (const int*)d_in[3];
    const float* W_AA = (const float*)d_in[4];
    const float* b_AA = (const float*)d_in[5];
    const float* W_PA = (const float*)d_in[6];
    const float* b_PA = (const float*)d_in[7];
    const float* W_A  = (const float*)d_in[8];
    const float* b_A  = (const float*)d_in[9];
    const float* W_AP = (const float*)d_in[10];
    const float* b_AP = (const float*)d_in[11];
    const float* W_PP = (const float*)d_in[12];
    const float* b_PP = (const float*)d_in[13];
    const float* W_P  = (const float*)d_in[14];
    const float* b_P  = (const float*)d_in[15];

    float* out   = (float*)d_out;
    float* A_out = out;                              // [NATOMS,50]
    float* P_out = out + (size_t)NATOMS * 50;        // [NPAIRS,50]

    float*        AA    = (float*)d_ws;                               // 5,000,000 f32
    unsigned int* XAu   = (unsigned int*)(AA + (size_t)NATOMS * 50);  // 5,600,000 u32
    float*        PAsum = (float*)(XAu + (size_t)NATOMS * 56);        // 5,000,000 f32

    hipMemsetAsync(PAsum, 0, (size_t)NATOMS * 50 * sizeof(float), stream);

    k_atom_pre<<<dim3(391, 2), 256, 0, stream>>>(
        atom_features, W_AA, b_AA, W_AP, b_AP, AA, XAu);

    k_pair<<<NPAIRS / 128, 256, 0, stream>>>(
        pair_features, pair_split, atom_to_pair,
        W_PA, b_PA, W_PP, b_PP, W_P, b_P,
        XAu, PAsum, P_out);

    k_atom_final<<<dim3(391, 2), 256, 0, stream>>>(
        AA, PAsum, W_A, b_A, A_out);
}